// Round 16
// baseline (219.401 us; speedup 1.0000x reference)
//
#include <hip/hip_runtime.h>
#include <math.h>

// Problem constants: B=64, N=512, d=64
#define NB 64
#define NN 512
#define ND 64

#define LOG2E 1.4426950408889634f
#define LN2   0.6931471805599453f
#define RING  8                       // prefetch ring depth per batch

typedef __attribute__((ext_vector_type(8))) short  bf16x8;  // 8 bf16 in 4 VGPRs
typedef __attribute__((ext_vector_type(4))) float  f32x4;

// fp32 -> bf16 bits, round-to-nearest-even (inputs are finite)
static __device__ __forceinline__ unsigned short f2bf(float f) {
    unsigned u = __float_as_uint(f);
    u += 0x7FFFu + ((u >> 16) & 1u);
    return (unsigned short)(u >> 16);
}

// ---------------------------------------------------------------------------
// Kernel 0 (pack): X,Y (f32 row-major) -> bf16 in MFMA-fragment order, plus
// fp32 row norms (R12-R15-proven, unchanged).
// ---------------------------------------------------------------------------
__global__ __launch_bounds__(256) void pack_kernel(const float* __restrict__ X,
                                                   const float* __restrict__ Y,
                                                   unsigned short* __restrict__ Xp,
                                                   unsigned short* __restrict__ Yp,
                                                   float* __restrict__ nx,
                                                   float* __restrict__ ny) {
    const int gid = blockIdx.x * 256 + threadIdx.x;   // row id, 0..NB*NN-1
    const float* src;
    unsigned short* dst;
    float* ndst;
    if (blockIdx.y == 0) { src = X + (size_t)gid * ND; dst = Xp; ndst = nx; }
    else                 { src = Y + (size_t)gid * ND; dst = Yp; ndst = ny; }

    float v[ND];
    float s = 0.f;
    #pragma unroll
    for (int k = 0; k < ND; k += 4) {
        float4 f = *(const float4*)(src + k);
        v[k] = f.x; v[k + 1] = f.y; v[k + 2] = f.z; v[k + 3] = f.w;
        s += f.x * f.x + f.y * f.y + f.z * f.z + f.w * f.w;
    }
    ndst[gid] = s;

    const int b  = gid >> 9;
    const int i  = gid & 511;
    const int it = i >> 4;             // 16-row tile
    const int lm = i & 15;             // row within tile
    #pragma unroll
    for (int h = 0; h < 2; ++h) {
        #pragma unroll
        for (int q = 0; q < 4; ++q) {
            unsigned w[4];
            #pragma unroll
            for (int m = 0; m < 4; ++m) {
                const int c = h * 32 + q * 8 + 2 * m;
                w[m] = (unsigned)f2bf(v[c]) | ((unsigned)f2bf(v[c + 1]) << 16);
            }
            uint4 pkt; pkt.x = w[0]; pkt.y = w[1]; pkt.z = w[2]; pkt.w = w[3];
            *(uint4*)(dst + ((((size_t)b * 32 + it) * 2 + h) << 9)
                          + (size_t)(q * 16 + lm) * 8) = pkt;
        }
    }
}

// ---------------------------------------------------------------------------
// Kernel 1 (MFMA): Wt[b][i][j] = bf16( exp2(16 - log2e*||X[b][i]-Y[b][j]||) )
// (R13-R15-proven, unchanged.)
// ---------------------------------------------------------------------------
__global__ __launch_bounds__(256) void cdist_kernel(const unsigned short* __restrict__ Xp,
                                                    const unsigned short* __restrict__ Yp,
                                                    const float* __restrict__ nx,
                                                    const float* __restrict__ ny,
                                                    unsigned short* __restrict__ Wt) {
    const int b  = blockIdx.z;
    const int ib = blockIdx.x * 128;   // i base (X rows)
    const int jb = blockIdx.y * 128;   // j base (Y rows)
    const int t  = threadIdx.x;

    const int wave = t >> 6;
    const int wi   = (wave & 1) * 64;   // i offset of this wave's 64x64 tile
    const int wj   = (wave >> 1) * 64;  // j offset
    const int lane = t & 63;
    const int lm   = lane & 15;
    const int quad = lane >> 4;

    f32x4 acc[4][4];
    #pragma unroll
    for (int mt = 0; mt < 4; ++mt)
        #pragma unroll
        for (int nt = 0; nt < 4; ++nt)
            acc[mt][nt] = (f32x4){0.f, 0.f, 0.f, 0.f};

    const int jt0 = (jb + wj) >> 4;    // Y tile base
    const int it0 = (ib + wi) >> 4;    // X tile base

    #pragma unroll
    for (int h = 0; h < 2; ++h) {
        bf16x8 Af[4], Bf[4];
        #pragma unroll
        for (int mt = 0; mt < 4; ++mt)   // A from Y tiles (m = j dim)
            Af[mt] = *(const bf16x8*)(Yp
                + ((((size_t)b * 32 + jt0 + mt) * 2 + h) << 9) + (size_t)lane * 8);
        #pragma unroll
        for (int nt = 0; nt < 4; ++nt)   // B from X tiles (n = i dim)
            Bf[nt] = *(const bf16x8*)(Xp
                + ((((size_t)b * 32 + it0 + nt) * 2 + h) << 9) + (size_t)lane * 8);
        #pragma unroll
        for (int mt = 0; mt < 4; ++mt)
            #pragma unroll
            for (int nt = 0; nt < 4; ++nt)
                acc[mt][nt] = __builtin_amdgcn_mfma_f32_16x16x32_bf16(
                    Af[mt], Bf[nt], acc[mt][nt], 0, 0, 0);
    }

    float nxv[4];
    float4 nyv[4];
    #pragma unroll
    for (int nt = 0; nt < 4; ++nt)
        nxv[nt] = nx[(size_t)b * NN + ib + wi + nt * 16 + lm];
    #pragma unroll
    for (int mt = 0; mt < 4; ++mt)
        nyv[mt] = *(const float4*)(ny + (size_t)b * NN + jb + wj + mt * 16 + quad * 4);

    #pragma unroll
    for (int nt = 0; nt < 4; ++nt) {
        const int i = ib + wi + nt * 16 + lm;
        unsigned short* Drow = Wt + ((size_t)b * NN + i) * NN + jb + wj;
        #pragma unroll
        for (int mt = 0; mt < 4; ++mt) {
            const float* nyp = (const float*)&nyv[mt];
            unsigned a[4];
            #pragma unroll
            for (int r = 0; r < 4; ++r) {
                float d2 = nyp[r] + nxv[nt] - 2.0f * acc[mt][nt][r];
                float w  = __builtin_amdgcn_exp2f(16.0f - LOG2E * sqrtf(fmaxf(d2, 0.f)));
                a[r] = __float_as_uint(w) + 0x8000u;   // round-half-up to bf16
            }
            uint2 pkt;
            pkt.x = (a[0] >> 16) | (a[1] & 0xFFFF0000u);
            pkt.y = (a[2] >> 16) | (a[3] & 0xFFFF0000u);
            *(uint2*)(Drow + mt * 16 + quad * 4) = pkt;
        }
    }
}

// ---------------------------------------------------------------------------
// Kernel 2: soft-DTW DP — single wave, 8 rows/lane (R11-proven structure),
// TWO BATCHES INTERLEAVED per wave (independent chains fill each other's
// stall slots: R11/R15 showed per-step cost ~fixed at 240-300 cyc regardless
// of rows/lane => overhead-dominated, so amortize it across 2 batches).
// Exp-domain chain + R15-proven bit-exact mantissa/exponent handoff
// (no transcendental on the chain; inf/NaN impossible by exponent clamp).
// No LDS, no barriers. Phases: A ss[0,72) act+guard+clamp; B [72,504)
// branchless; C [504,576) guard.
// ---------------------------------------------------------------------------
static __device__ __forceinline__ float dpp_shr1f(float x, float old) {
    return __int_as_float(__builtin_amdgcn_update_dpp(
        __float_as_int(old), __float_as_int(x), 0x138, 0xf, 0xf, false));
}
static __device__ __forceinline__ int dpp_shr1i(int x, int old) {
    return __builtin_amdgcn_update_dpp(old, x, 0x138, 0xf, 0xf, false);
}

struct DtwState {
    float L[8];
    float diagHold;
    float hm;
    int   he;
    int   Oti;
};

static __device__ __forceinline__ void half_step(
    bool DOACT, bool DOGUARD, bool DOCLAMP, bool DOREN,
    int ss, int u, int t, const unsigned short* __restrict__ Wb, int ib,
    uint4* ring, DtwState& S)
{
    // handoff in: lane t gets lane t-1's (hm,he); lane 0 gets sentinel F~0
    const float rm = dpp_shr1f(S.hm, 1.0f);
    const int   re = dpp_shr1i(S.he, -100000);
    if (DOACT) { if (ss == t && t > 0) S.Oti = -re; }   // adopt scale: up0=rm

    int sx = re + S.Oti;                       // stored-domain exponent
    sx = sx < -126 ? -126 : (sx > 60 ? 60 : sx);
    const float up0 = __uint_as_float(__float_as_uint(rm) + ((unsigned)sx << 23));
    const float diag0 = S.diagHold;
    S.diagHold = up0 * 65536.0f;

    const int j = ss - t + 1;
    const uint4 c = ring[u];

    {   // refill slot u for step ss+RING (unconditional; overrun is dead data)
        int jn = j + RING;
        if (DOCLAMP) jn = jn < 1 ? 1 : jn;
        ring[u] = *(const uint4*)(Wb + (size_t)(jn - 1) * NN + ib);
    }

    bool act = true;
    if (DOGUARD) act = (j >= 1) && (j <= NN);
    if (act) {
        float dd[8];                           // bf16 -> f32: shl/and, exact
        dd[0] = __uint_as_float(c.x << 16);
        dd[1] = __uint_as_float(c.x & 0xFFFF0000u);
        dd[2] = __uint_as_float(c.y << 16);
        dd[3] = __uint_as_float(c.y & 0xFFFF0000u);
        dd[4] = __uint_as_float(c.z << 16);
        dd[5] = __uint_as_float(c.z & 0xFFFF0000u);
        dd[6] = __uint_as_float(c.w << 16);
        dd[7] = __uint_as_float(c.w & 0xFFFF0000u);

        float pre[8], cc[8];
        pre[0] = diag0 + S.L[0];
        #pragma unroll
        for (int k = 1; k < 8; ++k)
            pre[k] = fmaf(65536.0f, S.L[k - 1], S.L[k]);
        #pragma unroll
        for (int k = 0; k < 8; ++k) cc[k] = dd[k] * pre[k];
        float r = up0;
        #pragma unroll
        for (int k = 0; k < 8; ++k) {          // serial chain: 8 fma
            r = fmaf(dd[k], r, cc[k]);
            S.L[k] = r;
        }

        if (DOREN) {   // branchless full normalization: max(L) -> [1,2)
            float m8 = fmaxf(fmaxf(fmaxf(S.L[0], S.L[1]), fmaxf(S.L[2], S.L[3])),
                             fmaxf(fmaxf(S.L[4], S.L[5]), fmaxf(S.L[6], S.L[7])));
            const int   e  = (int)(__float_as_uint(m8) >> 23) - 127;
            const float sc = __uint_as_float((unsigned)(127 - e) << 23); // 2^-e
            #pragma unroll
            for (int k = 0; k < 8; ++k) S.L[k] *= sc;
            S.diagHold *= sc;
            S.Oti -= e;
        }

        // handoff out: (hm,he) from L[7]'s raw bits — renorm-invariant
        const unsigned lb = __float_as_uint(S.L[7]);
        S.he = (int)(lb >> 23) - 127 - S.Oti;
        S.hm = __uint_as_float((lb & 0x007FFFFFu) | 0x3F800000u);
    }
}

__global__ __launch_bounds__(64) void dtw_kernel(const unsigned short* __restrict__ Wt,
                                                 float* __restrict__ out) {
    const int bp = blockIdx.x;                 // batch pair: batches 2bp, 2bp+1
    const int t  = threadIdx.x;                // lane 0..63
    const unsigned short* __restrict__ Wb0 = Wt + (size_t)(2 * bp) * NN * NN;
    const unsigned short* __restrict__ Wb1 = Wt + (size_t)(2 * bp + 1) * NN * NN;
    const int ib = 8 * t;                      // first owned row - 1

    DtwState S0, S1;
    #pragma unroll
    for (int k = 0; k < 8; ++k) { S0.L[k] = 0.f; S1.L[k] = 0.f; }
    S0.diagHold = (t == 0) ? 65536.0f : 0.0f;  // 2^16 * F[0][0]
    S1.diagHold = S0.diagHold;
    S0.hm = 1.0f; S1.hm = 1.0f;
    S0.he = -100000; S1.he = -100000;          // sentinel: F ~ 2^-100000 ~ 0
    S0.Oti = 0; S1.Oti = 0;

    uint4 ring0[RING], ring1[RING];
    #pragma unroll
    for (int u = 0; u < RING; ++u) {
        int col = u - t + 1;
        col = col < 1 ? 1 : col;               // clamp; dead if OOB
        ring0[u] = *(const uint4*)(Wb0 + (size_t)(col - 1) * NN + ib);
        ring1[u] = *(const uint4*)(Wb1 + (size_t)(col - 1) * NN + ib);
    }

    // Phase A: activation + guard + lower clamp (ss 0..71)
    for (int sb = 0; sb < 72; sb += RING)
        #pragma unroll
        for (int u = 0; u < RING; ++u) {
            half_step(true, true, true, (u & 1) == 1, sb + u, u, t, Wb0, ib, ring0, S0);
            half_step(true, true, true, (u & 1) == 1, sb + u, u, t, Wb1, ib, ring1, S1);
        }

    // Phase B: branchless hot loop (ss 72..503; all 64 lanes active)
    for (int sb = 72; sb < 504; sb += RING)
        #pragma unroll
        for (int u = 0; u < RING; ++u) {
            half_step(false, false, false, (u & 1) == 1, sb + u, u, t, Wb0, ib, ring0, S0);
            half_step(false, false, false, (u & 1) == 1, sb + u, u, t, Wb1, ib, ring1, S1);
        }

    // Phase C: drain with j<=NN guard (ss 504..575)
    for (int sb = 504; sb < 576; sb += RING)
        #pragma unroll
        for (int u = 0; u < RING; ++u) {
            half_step(false, true, false, (u & 1) == 1, sb + u, u, t, Wb0, ib, ring0, S0);
            half_step(false, true, false, (u & 1) == 1, sb + u, u, t, Wb1, ib, ring1, S1);
        }

    // F[512][512] = 2^(16*1024) e^{-R};  log2 F = he + log2(hm)
    if (t == 63) {
        out[2 * bp]     = (16384.0f - ((float)S0.he + __builtin_amdgcn_logf(S0.hm))) * LN2;
        out[2 * bp + 1] = (16384.0f - ((float)S1.he + __builtin_amdgcn_logf(S1.hm))) * LN2;
    }
}

extern "C" void kernel_launch(void* const* d_in, const int* in_sizes, int n_in,
                              void* d_out, int out_size, void* d_ws, size_t ws_size,
                              hipStream_t stream) {
    const float* X = (const float*)d_in[0];
    const float* Y = (const float*)d_in[1];
    float* out = (float*)d_out;

    // workspace layout (ws >= 64 MB):
    //   [0, 32 MB)      Wt  : bf16 W matrix, layout [b][i][j]
    //   [32, 36 MB)     Xp  : packed bf16 X fragments
    //   [36, 40 MB)     Yp  : packed bf16 Y fragments
    //   [40 MB, +128KB) nx  : fp32 row norms of X
    //   [+128KB,+256KB) ny  : fp32 row norms of Y
    char* ws = (char*)d_ws;
    unsigned short* Wt = (unsigned short*)(ws);
    unsigned short* Xp = (unsigned short*)(ws + (33554432));
    unsigned short* Yp = (unsigned short*)(ws + (33554432 + 4194304));
    float* nx = (float*)(ws + (33554432 + 2 * 4194304));
    float* ny = (float*)(ws + (33554432 + 2 * 4194304 + 131072));

    pack_kernel<<<dim3(NB * NN / 256, 2), 256, 0, stream>>>(X, Y, Xp, Yp, nx, ny);
    cdist_kernel<<<dim3(4, 4, NB), 256, 0, stream>>>(Xp, Yp, nx, ny, Wt);
    dtw_kernel<<<NB / 2, 64, 0, stream>>>(Wt, out);
}